// Round 15
// baseline (485.082 us; speedup 1.0000x reference)
//
#include <hip/hip_runtime.h>
#include <hip/hip_bf16.h>

#define B_ 64
#define N_ 4096
#define D_ 256
#define S_ 8
#define HID_ 512

typedef __attribute__((ext_vector_type(8))) short short8;
typedef __attribute__((ext_vector_type(4))) float f32x4;

__device__ inline unsigned int f2bf(float f){
  unsigned int x = __builtin_bit_cast(unsigned int, f);
  unsigned int r = x + 0x7fffu + ((x >> 16) & 1u);
  return (r >> 16);
}
__device__ inline float bf2f(unsigned int u){
  unsigned int x = (u & 0xffffu) << 16;
  return __builtin_bit_cast(float, x);
}
__device__ inline void fma8(short8 w8, const float* xp, float& a){
#pragma unroll
  for (int e = 0; e < 8; ++e) a += bf2f((unsigned)(unsigned short)w8[e]) * xp[e];
}

// ---------------- kernel LN: x_hat = LN(inputs) -> bf16 [B*N][256] ----------
__global__ __launch_bounds__(256) void kLN(const float* __restrict__ xin,
    const float* __restrict__ lng, const float* __restrict__ lnb,
    unsigned short* __restrict__ xh)
{
  const int t = threadIdx.x;
  const int wv = t >> 6, lane = t & 63;
  const float4 g4 = *(const float4*)(lng + lane * 4);
  const float4 b4 = *(const float4*)(lnb + lane * 4);
#pragma unroll 2
  for (int it = 0; it < 32; ++it){
    const long r = (long)it * 8192 + blockIdx.x * 4 + wv;
    float4 f = *(const float4*)(xin + r * 256 + lane * 4);
    float s  = f.x + f.y + f.z + f.w;
    float ss = f.x*f.x + f.y*f.y + f.z*f.z + f.w*f.w;
#pragma unroll
    for (int o = 1; o < 64; o <<= 1){ s += __shfl_xor(s, o); ss += __shfl_xor(ss, o); }
    const float mean = s * (1.f/256.f);
    const float rstd = rsqrtf(ss * (1.f/256.f) - mean * mean + 1e-5f);
    unsigned p0 = f2bf((f.x - mean)*rstd*g4.x + b4.x) | (f2bf((f.y - mean)*rstd*g4.y + b4.y) << 16);
    unsigned p1 = f2bf((f.z - mean)*rstd*g4.z + b4.z) | (f2bf((f.w - mean)*rstd*g4.w + b4.w) << 16);
    uint2 pk; pk.x = p0; pk.y = p1;
    *(uint2*)(xh + r * 256 + lane * 4) = pk;
  }
}

// ---------------- kernel Pre: fold weights (tiled, 65 blocks) ---------------
// blk 0..15:  M[d0+dd][t] = sum_e wk[e][d0+dd]*wq[e][t]; cb[d] = sum_e wk[e][d]*bq[e]
// blk 16..63: Wih2[g0+gg][t] = sum_d wih[g0+gg][d]*wv[d][t]; bih2 likewise
// blk 64:     v1[t] = sum_e wq[e][t]*bk[e]; c0 = bq.bk
__global__ __launch_bounds__(256) void kPre(
    const float* __restrict__ wq, const float* __restrict__ bq,
    const float* __restrict__ wk, const float* __restrict__ bk,
    const float* __restrict__ wv, const float* __restrict__ bv,
    const float* __restrict__ wih, const float* __restrict__ bih,
    float* __restrict__ Mb, float* __restrict__ cb,
    float* __restrict__ v1b, float* __restrict__ c0b,
    float* __restrict__ bih2,
    unsigned short* __restrict__ Mbh, unsigned short* __restrict__ Wih2h)
{
  __shared__ float tile[4096];           // 16 KB
  const int blk = blockIdx.x, t = threadIdx.x;
  if (blk < 16){
    const int d0 = blk * 16;
    // stage wk[:, d0..d0+15] as tile[e*16+dd]
#pragma unroll
    for (int r = 0; r < 16; ++r){
      const int idx = r * 256 + t;
      const int e = idx >> 4, dd = idx & 15;
      tile[idx] = wk[e*256 + d0 + dd];
    }
    __syncthreads();
    float acc[16], accc[16];
#pragma unroll
    for (int dd = 0; dd < 16; ++dd){ acc[dd] = 0.f; accc[dd] = 0.f; }
    for (int e = 0; e < 256; ++e){
      const float wqv = wq[e*256 + t];
      const float bqe = bq[e];
      const float4* kr = (const float4*)&tile[e*16];
      float4 k0 = kr[0], k1 = kr[1], k2 = kr[2], k3 = kr[3];
      acc[0]+=k0.x*wqv; acc[1]+=k0.y*wqv; acc[2]+=k0.z*wqv; acc[3]+=k0.w*wqv;
      acc[4]+=k1.x*wqv; acc[5]+=k1.y*wqv; acc[6]+=k1.z*wqv; acc[7]+=k1.w*wqv;
      acc[8]+=k2.x*wqv; acc[9]+=k2.y*wqv; acc[10]+=k2.z*wqv; acc[11]+=k2.w*wqv;
      acc[12]+=k3.x*wqv; acc[13]+=k3.y*wqv; acc[14]+=k3.z*wqv; acc[15]+=k3.w*wqv;
      accc[0]+=k0.x*bqe; accc[1]+=k0.y*bqe; accc[2]+=k0.z*bqe; accc[3]+=k0.w*bqe;
      accc[4]+=k1.x*bqe; accc[5]+=k1.y*bqe; accc[6]+=k1.z*bqe; accc[7]+=k1.w*bqe;
      accc[8]+=k2.x*bqe; accc[9]+=k2.y*bqe; accc[10]+=k2.z*bqe; accc[11]+=k2.w*bqe;
      accc[12]+=k3.x*bqe; accc[13]+=k3.y*bqe; accc[14]+=k3.z*bqe; accc[15]+=k3.w*bqe;
    }
#pragma unroll
    for (int dd = 0; dd < 16; ++dd){
      float v = acc[dd];
      Mb[(d0+dd)*256 + t] = v;
      Mbh[(d0+dd)*256 + t] = (unsigned short)f2bf(v);
    }
#pragma unroll
    for (int dd = 0; dd < 16; ++dd) if (t == dd) cb[d0+dd] = accc[dd];
  } else if (blk < 64){
    const int g0 = (blk - 16) * 16;
    // stage wih[g0..g0+15][:] as tile[gg*256+d] (coalesced row loads)
#pragma unroll
    for (int r = 0; r < 16; ++r) tile[r*256 + t] = wih[(long)(g0+r)*256 + t];
    __syncthreads();
    float acc[16], accb[16];
#pragma unroll
    for (int gg = 0; gg < 16; ++gg){ acc[gg] = 0.f; accb[gg] = 0.f; }
    for (int d = 0; d < 256; ++d){
      const float wvv = wv[d*256 + t];
      const float bvd = bv[d];
#pragma unroll
      for (int gg = 0; gg < 16; ++gg){
        float wg = tile[gg*256 + d];      // LDS broadcast
        acc[gg]  += wg * wvv;
        accb[gg] += wg * bvd;
      }
    }
#pragma unroll
    for (int gg = 0; gg < 16; ++gg)
      Wih2h[(long)(g0+gg)*256 + t] = (unsigned short)f2bf(acc[gg]);
#pragma unroll
    for (int gg = 0; gg < 16; ++gg) if (t == gg) bih2[g0+gg] = bih[g0+gg] + accb[gg];
  } else {
    float acc = 0.f, acc0 = 0.f;
    for (int e = 0; e < 256; ++e){
      float bke = bk[e];
      acc  += wq[e*256 + t] * bke;
      acc0 += bq[e] * bke;
    }
    v1b[t] = acc;
    if (t == 0) c0b[0] = acc0;
  }
}

// ---------------- kernel Cvt: w_hh / w1 / w2 -> bf16 ------------------------
__global__ __launch_bounds__(256) void kCvt(
    const float* __restrict__ w_hh, const float* __restrict__ w1,
    const float* __restrict__ w2,
    unsigned short* __restrict__ whhh, unsigned short* __restrict__ w1h,
    unsigned short* __restrict__ w2h)
{
  const int i = blockIdx.x * 256 + threadIdx.x;     // 0 .. 458751
  if (i < 196608) whhh[i] = (unsigned short)f2bf(w_hh[i]);
  else if (i < 327680) w1h[i - 196608] = (unsigned short)f2bf(w1[i - 196608]);
  else w2h[i - 327680] = (unsigned short)f2bf(w2[i - 327680]);
}

// ---------------- kernel I: slots init; qt = LN(slots)@M^T + c; d = s.v1+c0 --
__global__ __launch_bounds__(256) void kI(const float* __restrict__ init,
    const float* __restrict__ mu, const float* __restrict__ sig,
    const float* __restrict__ lsg, const float* __restrict__ lsb,
    const float* __restrict__ Mb, const float* __restrict__ cb,
    const float* __restrict__ v1b, const float* __restrict__ c0b,
    float* __restrict__ slots, float* __restrict__ qt, float* __restrict__ dbuf)
{
  const int b = blockIdx.x, t = threadIdx.x;
  __shared__ float xs[S_ * D_];
  __shared__ float red[4 * S_ * 2];
  __shared__ float redd[4 * S_];
  float sv[S_];
  const float muv = mu[t], sgv = sig[t];
#pragma unroll
  for (int i = 0; i < S_; ++i){
    float x = muv + sgv * init[(b*S_ + i)*D_ + t];
    sv[i] = x;
    slots[(b*S_ + i)*D_ + t] = x;
  }
  float s[S_], qq[S_];
#pragma unroll
  for (int i = 0; i < S_; ++i){ s[i] = sv[i]; qq[i] = sv[i]*sv[i]; }
#pragma unroll
  for (int o = 1; o < 64; o <<= 1){
#pragma unroll
    for (int i = 0; i < S_; ++i){ s[i] += __shfl_xor(s[i], o); qq[i] += __shfl_xor(qq[i], o); }
  }
  const int wv_ = t >> 6;
  if ((t & 63) == 0){
#pragma unroll
    for (int i = 0; i < S_; ++i){ red[(wv_*S_ + i)*2] = s[i]; red[(wv_*S_ + i)*2 + 1] = qq[i]; }
  }
  __syncthreads();
  const float g_ = lsg[t], bv_ = lsb[t];
#pragma unroll
  for (int i = 0; i < S_; ++i){
    float S0 = 0.f, Q0 = 0.f;
#pragma unroll
    for (int w2 = 0; w2 < 4; ++w2){ S0 += red[(w2*S_ + i)*2]; Q0 += red[(w2*S_ + i)*2 + 1]; }
    float mean = S0 * (1.f/256.f), var = Q0 * (1.f/256.f) - mean*mean;
    float rstd = rsqrtf(var + 1e-5f);
    xs[i*D_ + t] = (sv[i] - mean) * rstd * g_ + bv_;
  }
  __syncthreads();
  // ---- d_i = s_hat . v1 + c0
  {
    const float v1v = v1b[t];
    float pd[S_];
#pragma unroll
    for (int i = 0; i < S_; ++i) pd[i] = xs[i*D_ + t] * v1v;
#pragma unroll
    for (int o = 1; o < 64; o <<= 1)
#pragma unroll
      for (int i = 0; i < S_; ++i) pd[i] += __shfl_xor(pd[i], o);
    if ((t & 63) == 0){
#pragma unroll
      for (int i = 0; i < S_; ++i) redd[wv_*S_ + i] = pd[i];
    }
    __syncthreads();
    if (t < S_) dbuf[b*S_ + t] = redd[t] + redd[S_ + t] + redd[2*S_ + t] + redd[3*S_ + t] + c0b[0];
  }
  // ---- qt = s_hat @ M^T + c
  const float4* wr = (const float4*)(Mb + (long)t * D_);
  float acc[S_];
#pragma unroll
  for (int i = 0; i < S_; ++i) acc[i] = 0.f;
  for (int kc = 0; kc < 64; ++kc){
    float4 wf = wr[kc];
#pragma unroll
    for (int i = 0; i < S_; ++i){
      float4 xf = *(const float4*)(xs + i*D_ + kc*4);
      acc[i] += wf.x*xf.x + wf.y*xf.y + wf.z*xf.z + wf.w*xf.w;
    }
  }
  const float cbv = cb[t];
#pragma unroll
  for (int i = 0; i < S_; ++i) qt[(b*S_ + i)*D_ + t] = acc[i] + cbv;
}

// ---------------- kernel D: dots -> softmax -> PV, per-wave partials --------
// grid (16, 64), 256 thr. Wave-private throughout: sw rows owned per wave,
// and each wave writes its OWN global partial (chunk = ch*4+w, 64 chunks).
// No redbuf, no barriers after qs staging. LDS ~12.5 KB -> 4+ blocks/CU.
__global__ __launch_bounds__(256) void kD(const unsigned short* __restrict__ xh,
    const float* __restrict__ qt, const float* __restrict__ dbuf,
    float* __restrict__ numP, float* __restrict__ denP)
{
  const int b = blockIdx.y, ch = blockIdx.x, t = threadIdx.x;
  __shared__ __align__(16) unsigned short qs[16 * 264];
  __shared__ float sw[128 * 8];
  const int lane = t & 63, w = t >> 6;
  const int lr = lane & 15, lg = lane >> 4;
  const int oct = lane & 31, sh = lane >> 5;

  { // build qs (rows 0..7 = qt bf16, rows 8..15 = 0)
    const int rowq = t >> 4, segq = t & 15;
    uint4 z0 = {0,0,0,0}, z1 = {0,0,0,0};
    if (rowq < 8){
      const float* qr = qt + ((long)b * S_ + rowq) * D_ + segq * 16;
      float4 f0 = ((const float4*)qr)[0], f1 = ((const float4*)qr)[1];
      float4 f2 = ((const float4*)qr)[2], f3 = ((const float4*)qr)[3];
      z0.x = f2bf(f0.x)|(f2bf(f0.y)<<16); z0.y = f2bf(f0.z)|(f2bf(f0.w)<<16);
      z0.z = f2bf(f1.x)|(f2bf(f1.y)<<16); z0.w = f2bf(f1.z)|(f2bf(f1.w)<<16);
      z1.x = f2bf(f2.x)|(f2bf(f2.y)<<16); z1.y = f2bf(f2.z)|(f2bf(f2.w)<<16);
      z1.z = f2bf(f3.x)|(f2bf(f3.y)<<16); z1.w = f2bf(f3.z)|(f2bf(f3.w)<<16);
    }
    *(uint4*)(qs + rowq*264 + segq*16) = z0;
    *(uint4*)(qs + rowq*264 + segq*16 + 8) = z1;
  }
  __syncthreads();

  short8 bqf[8];
#pragma unroll
  for (int ks = 0; ks < 8; ++ks)
    bqf[ks] = *(const short8*)(qs + lr*264 + ks*32 + lg*8);

  const float dd = (lr < 8) ? dbuf[b*S_ + lr] * 0.0625f : 0.f;

  float acc4[4][8];
#pragma unroll
  for (int s = 0; s < 4; ++s)
#pragma unroll
    for (int e = 0; e < 8; ++e) acc4[s][e] = 0.f;
  float den4[4] = {0.f, 0.f, 0.f, 0.f};

  for (int ph = 0; ph < 2; ++ph){
    const long j0 = (long)ch * 256 + ph * 128;
    // ---- dots: wave w owns rows w*32 .. +32 (writes wave-private sw rows)
#pragma unroll
    for (int tau = 0; tau < 2; ++tau){
      const long jt = j0 + w*32 + tau*16;
      const unsigned short* kr = xh + ((long)b * N_ + jt + lr) * 256;
      f32x4 d = {0,0,0,0};
#pragma unroll
      for (int ks = 0; ks < 8; ++ks){
        short8 afk = *(const short8*)(kr + ks*32 + lg*8);
        d = __builtin_amdgcn_mfma_f32_16x16x32_bf16(afk, bqf[ks], d, 0, 0, 0);
      }
#pragma unroll
      for (int r = 0; r < 4; ++r){
        float x = d[r] * 0.0625f + dd;                // SCALE*(qt.xh) + d_i
        float m = x;
        m = fmaxf(m, __shfl_xor(m, 1));
        m = fmaxf(m, __shfl_xor(m, 2));
        m = fmaxf(m, __shfl_xor(m, 4));
        float e = __expf(x - m);
        float ssum = e;
        ssum += __shfl_xor(ssum, 1);
        ssum += __shfl_xor(ssum, 2);
        ssum += __shfl_xor(ssum, 4);
        float wv = e / ssum + 1e-8f;
        if (lr < 8) sw[(w*32 + tau*16 + lg*4 + r)*8 + lr] = wv;
      }
    }
    // (no barrier: sw rows w*32..+32 written & read by wave w only)
    // ---- PV: wave reads its 32 rows once; lane covers 4 slots x 8 d-elems
    const unsigned short* vrow = xh + ((long)b * N_ + j0 + w*32) * 256 + oct*8;
    const float* swr = sw + (w*32)*8 + sh*4;
#pragma unroll 4
    for (int j = 0; j < 32; ++j){
      uint4 v = *(const uint4*)(vrow + (long)j * 256);
      float4 w4 = *(const float4*)(swr + j*8);
      float xv[8];
      xv[0] = bf2f(v.x); xv[1] = bf2f(v.x >> 16);
      xv[2] = bf2f(v.y); xv[3] = bf2f(v.y >> 16);
      xv[4] = bf2f(v.z); xv[5] = bf2f(v.z >> 16);
      xv[6] = bf2f(v.w); xv[7] = bf2f(v.w >> 16);
#pragma unroll
      for (int e = 0; e < 8; ++e){
        acc4[0][e] += w4.x * xv[e];
        acc4[1][e] += w4.y * xv[e];
        acc4[2][e] += w4.z * xv[e];
        acc4[3][e] += w4.w * xv[e];
      }
      den4[0] += w4.x; den4[1] += w4.y; den4[2] += w4.z; den4[3] += w4.w;
    }
  }

  // ---- per-wave write-only partials (chunk = ch*4 + w)
  const int chw = ch * 4 + w;
#pragma unroll
  for (int s = 0; s < 4; ++s){
    const int slot = sh*4 + s;
    float* p = numP + (((long)chw * B_ + b) * S_ + slot) * D_ + oct*8;
    float4 a0 = {acc4[s][0], acc4[s][1], acc4[s][2], acc4[s][3]};
    float4 a1 = {acc4[s][4], acc4[s][5], acc4[s][6], acc4[s][7]};
    *(float4*)(p) = a0;
    *(float4*)(p + 4) = a1;
  }
  if (oct == 0){
#pragma unroll
    for (int s = 0; s < 4; ++s)
      denP[((long)b * S_ + sh*4 + s) * 64 + chw] = den4[s];
  }
}

// ---------------- kernel S: bf16 weights, u -> GRU -> MLP -> (qt|out) -------
__device__ inline void stats2(const float v[2], float* red, int t, float* mean, float* rstd){
  float s[2], q2[2];
#pragma unroll
  for (int ii = 0; ii < 2; ++ii){ s[ii] = v[ii]; q2[ii] = v[ii]*v[ii]; }
#pragma unroll
  for (int o = 1; o < 64; o <<= 1){
#pragma unroll
    for (int ii = 0; ii < 2; ++ii){ s[ii] += __shfl_xor(s[ii], o); q2[ii] += __shfl_xor(q2[ii], o); }
  }
  const int wv = t >> 6;
  if ((t & 63) == 0){
#pragma unroll
    for (int ii = 0; ii < 2; ++ii){ red[(wv*2 + ii)*2] = s[ii]; red[(wv*2 + ii)*2 + 1] = q2[ii]; }
  }
  __syncthreads();
#pragma unroll
  for (int ii = 0; ii < 2; ++ii){
    float S0 = 0.f, Q0 = 0.f;
#pragma unroll
    for (int w2 = 0; w2 < 4; ++w2){ S0 += red[(w2*2 + ii)*2]; Q0 += red[(w2*2 + ii)*2 + 1]; }
    float m = S0 * (1.f/256.f);
    float var = Q0 * (1.f/256.f) - m*m;
    mean[ii] = m; rstd[ii] = rsqrtf(var + 1e-5f);
  }
  __syncthreads();
}

__global__ __launch_bounds__(256) void kS(
    const float* __restrict__ numP, const float* __restrict__ denP,
    const float* __restrict__ slots_in,
    const unsigned short* __restrict__ Wih2h, const float* __restrict__ bih2,
    const unsigned short* __restrict__ whhh, const float* __restrict__ b_hh,
    const unsigned short* __restrict__ w1h, const float* __restrict__ b1,
    const unsigned short* __restrict__ w2h, const float* __restrict__ b2,
    const float* __restrict__ fg, const float* __restrict__ fb,
    const float* __restrict__ lsg, const float* __restrict__ lsb,
    const unsigned short* __restrict__ Mbh, const float* __restrict__ cbv,
    const float* __restrict__ v1b, const float* __restrict__ c0b,
    float* __restrict__ outp, float* __restrict__ qout, float* __restrict__ dbuf,
    int write_q)
{
  const int blk = blockIdx.x;            // 0..255
  const int b = blk >> 2, i0 = (blk & 3) * 2;
  const int t = threadIdx.x;
  const int grp = t >> 3, j = t & 7;
  __shared__ float us[2][D_], hs[2][D_], xs2[2][D_];
  __shared__ float gi_l[2][768], gh_l[2][768];
  __shared__ float h2s[2][HID_];
  __shared__ float o2[2][D_];
  __shared__ float red[4 * 2 * 2];
  const long base = (long)(b * S_ + i0) * D_;
#pragma unroll
  for (int ii = 0; ii < 2; ++ii){
    int si = b*S_ + i0 + ii;
    float dv = 0.f;
    for (int c = 0; c < 64; ++c) dv += denP[(long)si * 64 + c];
    float u = 0.f;
    for (int c = 0; c < 64; ++c)
      u += numP[(((long)c * B_ + b) * S_ + i0 + ii) * D_ + t];
    us[ii][t] = u / dv;
    hs[ii][t] = slots_in[base + ii*D_ + t];
  }
  __syncthreads();
  // ---- GRU gate GEMMs (bf16 weights): gi = u @ Wih2^T + bih2 ; gh = h @ w_hh^T
  for (int q = 0; q < 24; ++q){
    const int gcol = grp + q * 32;
    const short8* wi = (const short8*)(Wih2h + (long)gcol * D_);
    const short8* wh = (const short8*)(whhh + (long)gcol * D_);
    float ai[2] = {0,0}, ah[2] = {0,0};
#pragma unroll
    for (int c = 0; c < 4; ++c){
      const int u = j + c*8;               // short8 unit (covers cols u*8..+7)
      short8 wf = wi[u];
      short8 hf = wh[u];
#pragma unroll
      for (int ii = 0; ii < 2; ++ii){
        fma8(wf, &us[ii][u*8], ai[ii]);
        fma8(hf, &hs[ii][u*8], ah[ii]);
      }
    }
#pragma unroll
    for (int o = 1; o < 8; o <<= 1){
#pragma unroll
      for (int ii = 0; ii < 2; ++ii){ ai[ii] += __shfl_xor(ai[ii], o); ah[ii] += __shfl_xor(ah[ii], o); }
    }
    if (j == 0){
#pragma unroll
      for (int ii = 0; ii < 2; ++ii){ gi_l[ii][gcol] = ai[ii]; gh_l[ii][gcol] = ah[ii]; }
    }
  }
  __syncthreads();
  const float bir = bih2[t], biz = bih2[256 + t], bin_ = bih2[512 + t];
  const float bhr = b_hh[t], bhz = b_hh[256 + t], bhn = b_hh[512 + t];
  float nh[2];
#pragma unroll
  for (int ii = 0; ii < 2; ++ii){
    float r = 1.f / (1.f + __expf(-(gi_l[ii][t] + bir + gh_l[ii][t] + bhr)));
    float z = 1.f / (1.f + __expf(-(gi_l[ii][256 + t] + biz + gh_l[ii][256 + t] + bhz)));
    float n = tanhf(gi_l[ii][512 + t] + bin_ + r * (gh_l[ii][512 + t] + bhn));
    nh[ii] = (1.f - z) * n + z * hs[ii][t];
  }
  float mean[2], rstd[2];
  stats2(nh, red, t, mean, rstd);
  const float fgv = fg[t], fbv = fb[t];
#pragma unroll
  for (int ii = 0; ii < 2; ++ii) xs2[ii][t] = (nh[ii] - mean[ii]) * rstd[ii] * fgv + fbv;
  __syncthreads();
  // ---- MLP1 (bf16 weights) + relu
  for (int q = 0; q < 16; ++q){
    const int gcol = grp + q * 32;
    const short8* wr = (const short8*)(w1h + (long)gcol * D_);
    float a[2] = {0,0};
#pragma unroll
    for (int c = 0; c < 4; ++c){
      const int u = j + c*8;
      short8 wf = wr[u];
#pragma unroll
      for (int ii = 0; ii < 2; ++ii) fma8(wf, &xs2[ii][u*8], a[ii]);
    }
#pragma unroll
    for (int o = 1; o < 8; o <<= 1)
#pragma unroll
      for (int ii = 0; ii < 2; ++ii) a[ii] += __shfl_xor(a[ii], o);
    if (j == 0){
      float bb = b1[gcol];
#pragma unroll
      for (int ii = 0; ii < 2; ++ii) h2s[ii][gcol] = fmaxf(a[ii] + bb, 0.f);
    }
  }
  __syncthreads();
  // ---- MLP2 (bf16 weights, K=512)
  for (int q = 0; q < 8; ++q){
    const int gcol = grp + q * 32;
    const short8* wr = (const short8*)(w2h + (long)gcol * HID_);
    float a[2] = {0,0};
#pragma unroll
    for (int c = 0; c < 8; ++c){
      const int u = j + c*8;
      short8 wf = wr[u];
#pragma unroll
      for (int ii = 0; ii < 2; ++ii) fma8(wf, &h2s[ii][u*8], a[ii]);
    }
#pragma unroll
    for (int o = 1; o < 8; o <<= 1)
#pragma unroll
      for (int ii = 0; ii < 2; ++ii) a[ii] += __shfl_xor(a[ii], o);
    if (j == 0){
#pragma unroll
      for (int ii = 0; ii < 2; ++ii) o2[ii][gcol] = a[ii];
    }
  }
  __syncthreads();
  float outv[2];
  const float b2v = b2[t];
#pragma unroll
  for (int ii = 0; ii < 2; ++ii){
    outv[ii] = nh[ii] + o2[ii][t] + b2v;
    outp[base + ii*D_ + t] = outv[ii];
  }
  if (write_q){
    float mean2[2], rstd2[2];
    stats2(outv, red, t, mean2, rstd2);
    const float lg2 = lsg[t], lb2 = lsb[t];
#pragma unroll
    for (int ii = 0; ii < 2; ++ii) xs2[ii][t] = (outv[ii] - mean2[ii]) * rstd2[ii] * lg2 + lb2;
    __syncthreads();
    // ---- d_i = s_hat . v1 + c0
    {
      const float v1v = v1b[t];
      float pd[2];
#pragma unroll
      for (int ii = 0; ii < 2; ++ii) pd[ii] = xs2[ii][t] * v1v;
#pragma unroll
      for (int o = 1; o < 64; o <<= 1)
#pragma unroll
        for (int ii = 0; ii < 2; ++ii) pd[ii] += __shfl_xor(pd[ii], o);
      const int wv = t >> 6;
      if ((t & 63) == 0){ red[wv*2] = pd[0]; red[wv*2 + 1] = pd[1]; }
      __syncthreads();
      if (t < 2) dbuf[b*S_ + i0 + t] = red[t] + red[2 + t] + red[4 + t] + red[6 + t] + c0b[0];
    }
    // ---- qt = s_hat @ M^T + c (bf16 M)
    for (int q = 0; q < 8; ++q){
      const int gcol = grp + q * 32;
      const short8* wr = (const short8*)(Mbh + (long)gcol * D_);
      float a[2] = {0,0};
#pragma unroll
      for (int c = 0; c < 4; ++c){
        const int u = j + c*8;
        short8 wf = wr[u];
#pragma unroll
        for (int ii = 0; ii < 2; ++ii) fma8(wf, &xs2[ii][u*8], a[ii]);
      }
#pragma unroll
      for (int o = 1; o < 8; o <<= 1)
#pragma unroll
        for (int ii = 0; ii < 2; ++ii) a[ii] += __shfl_xor(a[ii], o);
      if (j == 0){
        float bb = cbv[gcol];
#pragma unroll
        for (int ii = 0; ii < 2; ++ii) qout[(long)(b*S_ + i0 + ii)*D_ + gcol] = a[ii] + bb;
      }
    }
  }
}

// ---------------- host ------------------------------------------------------
extern "C" void kernel_launch(void* const* d_in, const int* in_sizes, int n_in,
                              void* d_out, int out_size, void* d_ws, size_t ws_size,
                              hipStream_t stream)
{
  const float* inputs     = (const float*)d_in[0];
  const float* slots_init = (const float*)d_in[1];
  const float* slots_mu   = (const float*)d_in[2];
  const float* slots_sig  = (const float*)d_in[3];
  const float* wq   = (const float*)d_in[4];
  const float* bq   = (const float*)d_in[5];
  const float* wk   = (const float*)d_in[6];
  const float* bk   = (const float*)d_in[7];
  const float* wv   = (const float*)d_in[8];
  const float* bv   = (const float*)d_in[9];
  const float* w_ih = (const float*)d_in[10];
  const float* b_ih = (const float*)d_in[11];
  const float* w_hh = (const float*)d_in[12];
  const float* b_hh = (const float*)d_in[13];
  const float* w1   = (const float*)d_in[14];
  const float* b1   = (const float*)d_in[15];
  const float* w2   = (const float*)d_in[16];
  const float* b2   = (const float*)d_in[17];
  const float* lig  = (const float*)d_in[18];
  const float* lib  = (const float*)d_in[19];
  const float* lsg  = (const float*)d_in[20];
  const float* lsb  = (const float*)d_in[21];
  const float* ffg  = (const float*)d_in[22];
  const float* ffb  = (const float*)d_in[23];
  float* out = (float*)d_out;

  // ws layout (~170.1 MB). No memsets: numP/denP fully overwritten every kD
  // (64 per-wave chunks).
  //   qt    @ 0          (524,288)
  //   numP  @ 524,288    (33,554,432)  64-chunk per-wave partials
  //   denP  @ 34,078,720 (131,072)     [b][i][64]
  //   dbuf  @ 34,209,792 (2,048)
  //   Mb    @ 34,211,840 (262,144)     f32 (kI)
  //   cb    @ 34,473,984 (1,024)
  //   v1b   @ 34,475,008 (1,024)
  //   c0b   @ 34,476,032 (1,024)
  //   bih2  @ 34,477,056 (4,096)
  //   Mbh   @ 34,481,152 (131,072)     bf16 (kS)
  //   Wih2h @ 34,612,224 (393,216)     bf16
  //   whhh  @ 35,005,440 (393,216)     bf16
  //   w1h   @ 35,398,656 (262,144)     bf16
  //   w2h   @ 35,660,800 (262,144)     bf16
  //   xh    @ 35,922,944 (134,217,728) x_hat bf16 (L3-resident)
  // slots lives in d_out (in-place across iterations).
  char* ws = (char*)d_ws;
  float* qtb  = (float*)(ws);
  float* numP = (float*)(ws + 524288);
  float* denP = (float*)(ws + 34078720);
  float* dbuf = (float*)(ws + 34209792);
  float* Mb   = (float*)(ws + 34211840);
  float* cb   = (float*)(ws + 34473984);
  float* v1b  = (float*)(ws + 34475008);
  float* c0b  = (float*)(ws + 34476032);
  float* bih2 = (float*)(ws + 34477056);
  unsigned short* Mbh   = (unsigned short*)(ws + 34481152);
  unsigned short* Wih2h = (unsigned short*)(ws + 34612224);
  unsigned short* whhh  = (unsigned short*)(ws + 35005440);
  unsigned short* w1h   = (unsigned short*)(ws + 35398656);
  unsigned short* w2h   = (unsigned short*)(ws + 35660800);
  unsigned short* xh    = (unsigned short*)(ws + 35922944);
  float* slots = out;

  kLN<<<2048, 256, 0, stream>>>(inputs, lig, lib, xh);
  kPre<<<65, 256, 0, stream>>>(wq, bq, wk, bk, wv, bv, w_ih, b_ih,
                               Mb, cb, v1b, c0b, bih2, Mbh, Wih2h);
  kCvt<<<1792, 256, 0, stream>>>(w_hh, w1, w2, whhh, w1h, w2h);
  kI<<<64, 256, 0, stream>>>(slots_init, slots_mu, slots_sig, lsg, lsb,
                             Mb, cb, v1b, c0b, slots, qtb, dbuf);
  for (int it = 0; it < 3; ++it){
    kD<<<dim3(16, B_), 256, 0, stream>>>(xh, qtb, dbuf, numP, denP);
    kS<<<256, 256, 0, stream>>>(numP, denP, slots, Wih2h, bih2, whhh, b_hh,
                                w1h, b1, w2h, b2, ffg, ffb, lsg, lsb,
                                Mbh, cb, v1b, c0b,
                                slots, qtb, dbuf, (it < 2) ? 1 : 0);
  }
}

// Round 16
// 458.459 us; speedup vs baseline: 1.0581x; 1.0581x over previous
//
#include <hip/hip_runtime.h>
#include <hip/hip_bf16.h>

#define B_ 64
#define N_ 4096
#define D_ 256
#define S_ 8
#define HID_ 512
#define NCH_ 16

typedef __attribute__((ext_vector_type(8))) short short8;
typedef __attribute__((ext_vector_type(4))) float f32x4;

__device__ inline unsigned int f2bf(float f){
  unsigned int x = __builtin_bit_cast(unsigned int, f);
  unsigned int r = x + 0x7fffu + ((x >> 16) & 1u);
  return (r >> 16);
}
__device__ inline float bf2f(unsigned int u){
  unsigned int x = (u & 0xffffu) << 16;
  return __builtin_bit_cast(float, x);
}
__device__ inline void fma8(short8 w8, const float* xp, float& a){
#pragma unroll
  for (int e = 0; e < 8; ++e) a += bf2f((unsigned)(unsigned short)w8[e]) * xp[e];
}

// ---------------- kernel LN: x_hat = LN(inputs) -> bf16 [B*N][256] ----------
__global__ __launch_bounds__(256) void kLN(const float* __restrict__ xin,
    const float* __restrict__ lng, const float* __restrict__ lnb,
    unsigned short* __restrict__ xh)
{
  const int t = threadIdx.x;
  const int wv = t >> 6, lane = t & 63;
  const float4 g4 = *(const float4*)(lng + lane * 4);
  const float4 b4 = *(const float4*)(lnb + lane * 4);
#pragma unroll 2
  for (int it = 0; it < 32; ++it){
    const long r = (long)it * 8192 + blockIdx.x * 4 + wv;
    float4 f = *(const float4*)(xin + r * 256 + lane * 4);
    float s  = f.x + f.y + f.z + f.w;
    float ss = f.x*f.x + f.y*f.y + f.z*f.z + f.w*f.w;
#pragma unroll
    for (int o = 1; o < 64; o <<= 1){ s += __shfl_xor(s, o); ss += __shfl_xor(ss, o); }
    const float mean = s * (1.f/256.f);
    const float rstd = rsqrtf(ss * (1.f/256.f) - mean * mean + 1e-5f);
    unsigned p0 = f2bf((f.x - mean)*rstd*g4.x + b4.x) | (f2bf((f.y - mean)*rstd*g4.y + b4.y) << 16);
    unsigned p1 = f2bf((f.z - mean)*rstd*g4.z + b4.z) | (f2bf((f.w - mean)*rstd*g4.w + b4.w) << 16);
    uint2 pk; pk.x = p0; pk.y = p1;
    *(uint2*)(xh + r * 256 + lane * 4) = pk;
  }
}

// ---------------- kernel Pre: fold weights (tiled) + bf16 converts ----------
// blk 0..15:   M tiles; blk 16..63: Wih2 tiles; blk 64: v1/c0;
// blk 65..1856: kCvt (w_hh/w1/w2 -> bf16)
__global__ __launch_bounds__(256) void kPre(
    const float* __restrict__ wq, const float* __restrict__ bq,
    const float* __restrict__ wk, const float* __restrict__ bk,
    const float* __restrict__ wv, const float* __restrict__ bv,
    const float* __restrict__ wih, const float* __restrict__ bih,
    const float* __restrict__ w_hh, const float* __restrict__ w1,
    const float* __restrict__ w2,
    float* __restrict__ Mb, float* __restrict__ cb,
    float* __restrict__ v1b, float* __restrict__ c0b,
    float* __restrict__ bih2,
    unsigned short* __restrict__ Mbh, unsigned short* __restrict__ Wih2h,
    unsigned short* __restrict__ whhh, unsigned short* __restrict__ w1h,
    unsigned short* __restrict__ w2h)
{
  __shared__ float tile[4096];           // 16 KB
  const int blk = blockIdx.x, t = threadIdx.x;
  if (blk < 16){
    const int d0 = blk * 16;
#pragma unroll
    for (int r = 0; r < 16; ++r){
      const int idx = r * 256 + t;
      const int e = idx >> 4, dd = idx & 15;
      tile[idx] = wk[e*256 + d0 + dd];
    }
    __syncthreads();
    float acc[16], accc[16];
#pragma unroll
    for (int dd = 0; dd < 16; ++dd){ acc[dd] = 0.f; accc[dd] = 0.f; }
    for (int e = 0; e < 256; ++e){
      const float wqv = wq[e*256 + t];
      const float bqe = bq[e];
      const float4* kr = (const float4*)&tile[e*16];
      float4 k0 = kr[0], k1 = kr[1], k2 = kr[2], k3 = kr[3];
      acc[0]+=k0.x*wqv; acc[1]+=k0.y*wqv; acc[2]+=k0.z*wqv; acc[3]+=k0.w*wqv;
      acc[4]+=k1.x*wqv; acc[5]+=k1.y*wqv; acc[6]+=k1.z*wqv; acc[7]+=k1.w*wqv;
      acc[8]+=k2.x*wqv; acc[9]+=k2.y*wqv; acc[10]+=k2.z*wqv; acc[11]+=k2.w*wqv;
      acc[12]+=k3.x*wqv; acc[13]+=k3.y*wqv; acc[14]+=k3.z*wqv; acc[15]+=k3.w*wqv;
      accc[0]+=k0.x*bqe; accc[1]+=k0.y*bqe; accc[2]+=k0.z*bqe; accc[3]+=k0.w*bqe;
      accc[4]+=k1.x*bqe; accc[5]+=k1.y*bqe; accc[6]+=k1.z*bqe; accc[7]+=k1.w*bqe;
      accc[8]+=k2.x*bqe; accc[9]+=k2.y*bqe; accc[10]+=k2.z*bqe; accc[11]+=k2.w*bqe;
      accc[12]+=k3.x*bqe; accc[13]+=k3.y*bqe; accc[14]+=k3.z*bqe; accc[15]+=k3.w*bqe;
    }
#pragma unroll
    for (int dd = 0; dd < 16; ++dd){
      float v = acc[dd];
      Mb[(d0+dd)*256 + t] = v;
      Mbh[(d0+dd)*256 + t] = (unsigned short)f2bf(v);
    }
#pragma unroll
    for (int dd = 0; dd < 16; ++dd) if (t == dd) cb[d0+dd] = accc[dd];
  } else if (blk < 64){
    const int g0 = (blk - 16) * 16;
#pragma unroll
    for (int r = 0; r < 16; ++r) tile[r*256 + t] = wih[(long)(g0+r)*256 + t];
    __syncthreads();
    float acc[16], accb[16];
#pragma unroll
    for (int gg = 0; gg < 16; ++gg){ acc[gg] = 0.f; accb[gg] = 0.f; }
    for (int d = 0; d < 256; ++d){
      const float wvv = wv[d*256 + t];
      const float bvd = bv[d];
#pragma unroll
      for (int gg = 0; gg < 16; ++gg){
        float wg = tile[gg*256 + d];
        acc[gg]  += wg * wvv;
        accb[gg] += wg * bvd;
      }
    }
#pragma unroll
    for (int gg = 0; gg < 16; ++gg)
      Wih2h[(long)(g0+gg)*256 + t] = (unsigned short)f2bf(acc[gg]);
#pragma unroll
    for (int gg = 0; gg < 16; ++gg) if (t == gg) bih2[g0+gg] = bih[g0+gg] + accb[gg];
  } else if (blk == 64){
    float acc = 0.f, acc0 = 0.f;
    for (int e = 0; e < 256; ++e){
      float bke = bk[e];
      acc  += wq[e*256 + t] * bke;
      acc0 += bq[e] * bke;
    }
    v1b[t] = acc;
    if (t == 0) c0b[0] = acc0;
  } else {
    const int i = (blk - 65) * 256 + t;             // 0 .. 458751
    if (i < 196608) whhh[i] = (unsigned short)f2bf(w_hh[i]);
    else if (i < 327680) w1h[i - 196608] = (unsigned short)f2bf(w1[i - 196608]);
    else w2h[i - 327680] = (unsigned short)f2bf(w2[i - 327680]);
  }
}

// ---------------- kernel I: slots init; qt = LN(slots)@M^T + c; d = s.v1+c0 --
__global__ __launch_bounds__(256) void kI(const float* __restrict__ init,
    const float* __restrict__ mu, const float* __restrict__ sig,
    const float* __restrict__ lsg, const float* __restrict__ lsb,
    const float* __restrict__ Mb, const float* __restrict__ cb,
    const float* __restrict__ v1b, const float* __restrict__ c0b,
    float* __restrict__ slots, float* __restrict__ qt, float* __restrict__ dbuf)
{
  const int b = blockIdx.x, t = threadIdx.x;
  __shared__ float xs[S_ * D_];
  __shared__ float red[4 * S_ * 2];
  __shared__ float redd[4 * S_];
  float sv[S_];
  const float muv = mu[t], sgv = sig[t];
#pragma unroll
  for (int i = 0; i < S_; ++i){
    float x = muv + sgv * init[(b*S_ + i)*D_ + t];
    sv[i] = x;
    slots[(b*S_ + i)*D_ + t] = x;
  }
  float s[S_], qq[S_];
#pragma unroll
  for (int i = 0; i < S_; ++i){ s[i] = sv[i]; qq[i] = sv[i]*sv[i]; }
#pragma unroll
  for (int o = 1; o < 64; o <<= 1){
#pragma unroll
    for (int i = 0; i < S_; ++i){ s[i] += __shfl_xor(s[i], o); qq[i] += __shfl_xor(qq[i], o); }
  }
  const int wv_ = t >> 6;
  if ((t & 63) == 0){
#pragma unroll
    for (int i = 0; i < S_; ++i){ red[(wv_*S_ + i)*2] = s[i]; red[(wv_*S_ + i)*2 + 1] = qq[i]; }
  }
  __syncthreads();
  const float g_ = lsg[t], bv_ = lsb[t];
#pragma unroll
  for (int i = 0; i < S_; ++i){
    float S0 = 0.f, Q0 = 0.f;
#pragma unroll
    for (int w2 = 0; w2 < 4; ++w2){ S0 += red[(w2*S_ + i)*2]; Q0 += red[(w2*S_ + i)*2 + 1]; }
    float mean = S0 * (1.f/256.f), var = Q0 * (1.f/256.f) - mean*mean;
    float rstd = rsqrtf(var + 1e-5f);
    xs[i*D_ + t] = (sv[i] - mean) * rstd * g_ + bv_;
  }
  __syncthreads();
  // ---- d_i = s_hat . v1 + c0
  {
    const float v1v = v1b[t];
    float pd[S_];
#pragma unroll
    for (int i = 0; i < S_; ++i) pd[i] = xs[i*D_ + t] * v1v;
#pragma unroll
    for (int o = 1; o < 64; o <<= 1)
#pragma unroll
      for (int i = 0; i < S_; ++i) pd[i] += __shfl_xor(pd[i], o);
    if ((t & 63) == 0){
#pragma unroll
      for (int i = 0; i < S_; ++i) redd[wv_*S_ + i] = pd[i];
    }
    __syncthreads();
    if (t < S_) dbuf[b*S_ + t] = redd[t] + redd[S_ + t] + redd[2*S_ + t] + redd[3*S_ + t] + c0b[0];
  }
  // ---- qt = s_hat @ M^T + c
  const float4* wr = (const float4*)(Mb + (long)t * D_);
  float acc[S_];
#pragma unroll
  for (int i = 0; i < S_; ++i) acc[i] = 0.f;
  for (int kc = 0; kc < 64; ++kc){
    float4 wf = wr[kc];
#pragma unroll
    for (int i = 0; i < S_; ++i){
      float4 xf = *(const float4*)(xs + i*D_ + kc*4);
      acc[i] += wf.x*xf.x + wf.y*xf.y + wf.z*xf.z + wf.w*xf.w;
    }
  }
  const float cbv = cb[t];
#pragma unroll
  for (int i = 0; i < S_; ++i) qt[(b*S_ + i)*D_ + t] = acc[i] + cbv;
}

// ---------------- kernel D: dots -> softmax -> PV (R12/R14 proven) ----------
__global__ __launch_bounds__(256) void kD(const unsigned short* __restrict__ xh,
    const float* __restrict__ qt, const float* __restrict__ dbuf,
    float* __restrict__ numP, float* __restrict__ denP)
{
  const int b = blockIdx.y, ch = blockIdx.x, t = threadIdx.x;
  __shared__ __align__(16) char smem[4 * 64 * 37 * 4];      // qs overlay / redbuf
  __shared__ __align__(16) float sw[128 * 8];               // [row][slot]
  unsigned short* qs = (unsigned short*)smem;               // 16 x 264
  float* redbuf = (float*)smem;                             // 4 x 64 x 37
  const int lane = t & 63, w = t >> 6;
  const int lr = lane & 15, lg = lane >> 4;
  const int oct = lane & 31, sh = lane >> 5;

  { // build qs (rows 0..7 = qt bf16, rows 8..15 = 0)
    const int rowq = t >> 4, segq = t & 15;
    uint4 z0 = {0,0,0,0}, z1 = {0,0,0,0};
    if (rowq < 8){
      const float* qr = qt + ((long)b * S_ + rowq) * D_ + segq * 16;
      float4 f0 = ((const float4*)qr)[0], f1 = ((const float4*)qr)[1];
      float4 f2 = ((const float4*)qr)[2], f3 = ((const float4*)qr)[3];
      z0.x = f2bf(f0.x)|(f2bf(f0.y)<<16); z0.y = f2bf(f0.z)|(f2bf(f0.w)<<16);
      z0.z = f2bf(f1.x)|(f2bf(f1.y)<<16); z0.w = f2bf(f1.z)|(f2bf(f1.w)<<16);
      z1.x = f2bf(f2.x)|(f2bf(f2.y)<<16); z1.y = f2bf(f2.z)|(f2bf(f2.w)<<16);
      z1.z = f2bf(f3.x)|(f2bf(f3.y)<<16); z1.w = f2bf(f3.z)|(f2bf(f3.w)<<16);
    }
    *(uint4*)(qs + rowq*264 + segq*16) = z0;
    *(uint4*)(qs + rowq*264 + segq*16 + 8) = z1;
  }
  __syncthreads();

  short8 bqf[8];
#pragma unroll
  for (int ks = 0; ks < 8; ++ks)
    bqf[ks] = *(const short8*)(qs + lr*264 + ks*32 + lg*8);
  __syncthreads();                         // qs dead; redbuf may reuse smem

  const float dd = (lr < 8) ? dbuf[b*S_ + lr] * 0.0625f : 0.f;

  float acc4[4][8];
#pragma unroll
  for (int s = 0; s < 4; ++s)
#pragma unroll
    for (int e = 0; e < 8; ++e) acc4[s][e] = 0.f;
  float den4[4] = {0.f, 0.f, 0.f, 0.f};

  for (int ph = 0; ph < 2; ++ph){
    const long j0 = (long)ch * 256 + ph * 128;
    // ---- dots: wave w owns rows w*32 .. +32 (writes wave-private sw rows)
#pragma unroll
    for (int tau = 0; tau < 2; ++tau){
      const long jt = j0 + w*32 + tau*16;
      const unsigned short* kr = xh + ((long)b * N_ + jt + lr) * 256;
      f32x4 d = {0,0,0,0};
#pragma unroll
      for (int ks = 0; ks < 8; ++ks){
        short8 afk = *(const short8*)(kr + ks*32 + lg*8);
        d = __builtin_amdgcn_mfma_f32_16x16x32_bf16(afk, bqf[ks], d, 0, 0, 0);
      }
#pragma unroll
      for (int r = 0; r < 4; ++r){
        float x = d[r] * 0.0625f + dd;                // SCALE*(qt.xh) + d_i
        float m = x;
        m = fmaxf(m, __shfl_xor(m, 1));
        m = fmaxf(m, __shfl_xor(m, 2));
        m = fmaxf(m, __shfl_xor(m, 4));
        float e = __expf(x - m);
        float ssum = e;
        ssum += __shfl_xor(ssum, 1);
        ssum += __shfl_xor(ssum, 2);
        ssum += __shfl_xor(ssum, 4);
        float wv = e / ssum + 1e-8f;
        if (lr < 8) sw[(w*32 + tau*16 + lg*4 + r)*8 + lr] = wv;
      }
    }
    // (no barrier: sw rows w*32..+32 written & read by wave w only)
    // ---- PV: wave reads its 32 rows once; lane covers 4 slots x 8 d-elems
    const unsigned short* vrow = xh + ((long)b * N_ + j0 + w*32) * 256 + oct*8;
    const float* swr = sw + (w*32)*8 + sh*4;
#pragma unroll 4
    for (int j = 0; j < 32; ++j){
      uint4 v = *(const uint4*)(vrow + (long)j * 256);
      float4 w4 = *(const float4*)(swr + j*8);
      float xv[8];
      xv[0] = bf2f(v.x); xv[1] = bf2f(v.x >> 16);
      xv[2] = bf2f(v.y); xv[3] = bf2f(v.y >> 16);
      xv[4] = bf2f(v.z); xv[5] = bf2f(v.z >> 16);
      xv[6] = bf2f(v.w); xv[7] = bf2f(v.w >> 16);
#pragma unroll
      for (int e = 0; e < 8; ++e){
        acc4[0][e] += w4.x * xv[e];
        acc4[1][e] += w4.y * xv[e];
        acc4[2][e] += w4.z * xv[e];
        acc4[3][e] += w4.w * xv[e];
      }
      den4[0] += w4.x; den4[1] += w4.y; den4[2] += w4.z; den4[3] += w4.w;
    }
  }

  // ---- cross-wave reduce via redbuf (stride 37: conflict-free)
  __syncthreads();                         // all waves done with dots/PV
  {
    float* myred = redbuf + (w*64 + lane)*37;
#pragma unroll
    for (int s = 0; s < 4; ++s){
#pragma unroll
      for (int e = 0; e < 8; ++e) myred[s*8 + e] = acc4[s][e];
      myred[32 + s] = den4[s];
    }
  }
  __syncthreads();
  {
    const int i_ = t >> 5, oo = t & 31;
    const int ssh = i_ >> 2, ss = i_ & 3;
    float outv[8] = {0,0,0,0,0,0,0,0};
    float den = 0.f;
#pragma unroll
    for (int wv2 = 0; wv2 < 4; ++wv2){
      const float* p = redbuf + (wv2*64 + ssh*32 + oo)*37;
#pragma unroll
      for (int e = 0; e < 8; ++e) outv[e] += p[ss*8 + e];
      den += p[32 + ss];
    }
    float* numC = numP + ((((long)ch * B_ + b) * S_ + i_) * D_) + oo * 8;
    float4 a0 = {outv[0], outv[1], outv[2], outv[3]};
    float4 a1 = {outv[4], outv[5], outv[6], outv[7]};
    *(float4*)(numC) = a0;
    *(float4*)(numC + 4) = a1;
    if (oo == 0) denP[((long)b * S_ + i_) * NCH_ + ch] = den;
  }
}

// ---------------- kernel S: bf16 weights, u -> GRU -> MLP -> (qt|out) -------
__device__ inline void stats2(const float v[2], float* red, int t, float* mean, float* rstd){
  float s[2], q2[2];
#pragma unroll
  for (int ii = 0; ii < 2; ++ii){ s[ii] = v[ii]; q2[ii] = v[ii]*v[ii]; }
#pragma unroll
  for (int o = 1; o < 64; o <<= 1){
#pragma unroll
    for (int ii = 0; ii < 2; ++ii){ s[ii] += __shfl_xor(s[ii], o); q2[ii] += __shfl_xor(q2[ii], o); }
  }
  const int wv = t >> 6;
  if ((t & 63) == 0){
#pragma unroll
    for (int ii = 0; ii < 2; ++ii){ red[(wv*2 + ii)*2] = s[ii]; red[(wv*2 + ii)*2 + 1] = q2[ii]; }
  }
  __syncthreads();
#pragma unroll
  for (int ii = 0; ii < 2; ++ii){
    float S0 = 0.f, Q0 = 0.f;
#pragma unroll
    for (int w2 = 0; w2 < 4; ++w2){ S0 += red[(w2*2 + ii)*2]; Q0 += red[(w2*2 + ii)*2 + 1]; }
    float m = S0 * (1.f/256.f);
    float var = Q0 * (1.f/256.f) - m*m;
    mean[ii] = m; rstd[ii] = rsqrtf(var + 1e-5f);
  }
  __syncthreads();
}

__global__ __launch_bounds__(256) void kS(
    const float* __restrict__ numP, const float* __restrict__ denP,
    const float* __restrict__ slots_in,
    const unsigned short* __restrict__ Wih2h, const float* __restrict__ bih2,
    const unsigned short* __restrict__ whhh, const float* __restrict__ b_hh,
    const unsigned short* __restrict__ w1h, const float* __restrict__ b1,
    const unsigned short* __restrict__ w2h, const float* __restrict__ b2,
    const float* __restrict__ fg, const float* __restrict__ fb,
    const float* __restrict__ lsg, const float* __restrict__ lsb,
    const unsigned short* __restrict__ Mbh, const float* __restrict__ cbv,
    const float* __restrict__ v1b, const float* __restrict__ c0b,
    float* __restrict__ outp, float* __restrict__ qout, float* __restrict__ dbuf,
    int write_q)
{
  const int blk = blockIdx.x;            // 0..255
  const int b = blk >> 2, i0 = (blk & 3) * 2;
  const int t = threadIdx.x;
  const int grp = t >> 3, j = t & 7;
  __shared__ float us[2][D_], hs[2][D_], xs2[2][D_];
  __shared__ float gi_l[2][768], gh_l[2][768];
  __shared__ float h2s[2][HID_];
  __shared__ float o2[2][D_];
  __shared__ float red[4 * 2 * 2];
  const long base = (long)(b * S_ + i0) * D_;
#pragma unroll
  for (int ii = 0; ii < 2; ++ii){
    int si = b*S_ + i0 + ii;
    float dv = 0.f;
#pragma unroll
    for (int ch = 0; ch < NCH_; ++ch) dv += denP[(long)si * NCH_ + ch];
    float u = 0.f;
    for (int ch = 0; ch < NCH_; ++ch)
      u += numP[(((long)ch * B_ + b) * S_ + i0 + ii) * D_ + t];
    us[ii][t] = u / dv;
    hs[ii][t] = slots_in[base + ii*D_ + t];
  }
  __syncthreads();
  // ---- GRU gate GEMMs (bf16 weights): gi = u @ Wih2^T + bih2 ; gh = h @ w_hh^T
  for (int q = 0; q < 24; ++q){
    const int gcol = grp + q * 32;
    const short8* wi = (const short8*)(Wih2h + (long)gcol * D_);
    const short8* wh = (const short8*)(whhh + (long)gcol * D_);
    float ai[2] = {0,0}, ah[2] = {0,0};
#pragma unroll
    for (int c = 0; c < 4; ++c){
      const int u = j + c*8;               // short8 unit (covers cols u*8..+7)
      short8 wf = wi[u];
      short8 hf = wh[u];
#pragma unroll
      for (int ii = 0; ii < 2; ++ii){
        fma8(wf, &us[ii][u*8], ai[ii]);
        fma8(hf, &hs[ii][u*8], ah[ii]);
      }
    }
#pragma unroll
    for (int o = 1; o < 8; o <<= 1){
#pragma unroll
      for (int ii = 0; ii < 2; ++ii){ ai[ii] += __shfl_xor(ai[ii], o); ah[ii] += __shfl_xor(ah[ii], o); }
    }
    if (j == 0){
#pragma unroll
      for (int ii = 0; ii < 2; ++ii){ gi_l[ii][gcol] = ai[ii]; gh_l[ii][gcol] = ah[ii]; }
    }
  }
  __syncthreads();
  const float bir = bih2[t], biz = bih2[256 + t], bin_ = bih2[512 + t];
  const float bhr = b_hh[t], bhz = b_hh[256 + t], bhn = b_hh[512 + t];
  float nh[2];
#pragma unroll
  for (int ii = 0; ii < 2; ++ii){
    float r = 1.f / (1.f + __expf(-(gi_l[ii][t] + bir + gh_l[ii][t] + bhr)));
    float z = 1.f / (1.f + __expf(-(gi_l[ii][256 + t] + biz + gh_l[ii][256 + t] + bhz)));
    float n = tanhf(gi_l[ii][512 + t] + bin_ + r * (gh_l[ii][512 + t] + bhn));
    nh[ii] = (1.f - z) * n + z * hs[ii][t];
  }
  float mean[2], rstd[2];
  stats2(nh, red, t, mean, rstd);
  const float fgv = fg[t], fbv = fb[t];
#pragma unroll
  for (int ii = 0; ii < 2; ++ii) xs2[ii][t] = (nh[ii] - mean[ii]) * rstd[ii] * fgv + fbv;
  __syncthreads();
  // ---- MLP1 (bf16 weights) + relu
  for (int q = 0; q < 16; ++q){
    const int gcol = grp + q * 32;
    const short8* wr = (const short8*)(w1h + (long)gcol * D_);
    float a[2] = {0,0};
#pragma unroll
    for (int c = 0; c < 4; ++c){
      const int u = j + c*8;
      short8 wf = wr[u];
#pragma unroll
      for (int ii = 0; ii < 2; ++ii) fma8(wf, &xs2[ii][u*8], a[ii]);
    }
#pragma unroll
    for (int o = 1; o < 8; o <<= 1)
#pragma unroll
      for (int ii = 0; ii < 2; ++ii) a[ii] += __shfl_xor(a[ii], o);
    if (j == 0){
      float bb = b1[gcol];
#pragma unroll
      for (int ii = 0; ii < 2; ++ii) h2s[ii][gcol] = fmaxf(a[ii] + bb, 0.f);
    }
  }
  __syncthreads();
  // ---- MLP2 (bf16 weights, K=512)
  for (int q = 0; q < 8; ++q){
    const int gcol = grp + q * 32;
    const short8* wr = (const short8*)(w2h + (long)gcol * HID_);
    float a[2] = {0,0};
#pragma unroll
    for (int c = 0; c < 8; ++c){
      const int u = j + c*8;
      short8 wf = wr[u];
#pragma unroll
      for (int ii = 0; ii < 2; ++ii) fma8(wf, &h2s[ii][u*8], a[ii]);
    }
#pragma unroll
    for (int o = 1; o < 8; o <<= 1)
#pragma unroll
      for (int ii = 0; ii < 2; ++ii) a[ii] += __shfl_xor(a[ii], o);
    if (j == 0){
#pragma unroll
      for (int ii = 0; ii < 2; ++ii) o2[ii][gcol] = a[ii];
    }
  }
  __syncthreads();
  float outv[2];
  const float b2v = b2[t];
#pragma unroll
  for (int ii = 0; ii < 2; ++ii){
    outv[ii] = nh[ii] + o2[ii][t] + b2v;
    outp[base + ii*D_ + t] = outv[ii];
  }
  if (write_q){
    float mean2[2], rstd2[2];
    stats2(outv, red, t, mean2, rstd2);
    const float lg2 = lsg[t], lb2 = lsb[t];
#pragma unroll
    for (int ii = 0; ii < 2; ++ii) xs2[ii][t] = (outv[ii] - mean2[ii]) * rstd2[ii] * lg2 + lb2;
    __syncthreads();
    // ---- d_i = s_hat . v1 + c0
    {
      const float v1v = v1b[t];
      float pd[2];
#pragma unroll
      for (int ii = 0; ii < 2; ++ii) pd[ii] = xs2[ii][t] * v1v;
#pragma unroll
      for (int o = 1; o < 64; o <<= 1)
#pragma unroll
        for (int ii = 0; ii < 2; ++ii) pd[ii] += __shfl_xor(pd[ii], o);
      const int wv = t >> 6;
      if ((t & 63) == 0){ red[wv*2] = pd[0]; red[wv*2 + 1] = pd[1]; }
      __syncthreads();
      if (t < 2) dbuf[b*S_ + i0 + t] = red[t] + red[2 + t] + red[4 + t] + red[6 + t] + c0b[0];
    }
    // ---- qt = s_hat @ M^T + c (bf16 M)
    for (int q = 0; q < 8; ++q){
      const int gcol = grp + q * 32;
      const short8* wr = (const short8*)(Mbh + (long)gcol * D_);
      float a[2] = {0,0};
#pragma unroll
      for (int c = 0; c < 4; ++c){
        const int u = j + c*8;
        short8 wf = wr[u];
#pragma unroll
        for (int ii = 0; ii < 2; ++ii) fma8(wf, &xs2[ii][u*8], a[ii]);
      }
#pragma unroll
      for (int o = 1; o < 8; o <<= 1)
#pragma unroll
        for (int ii = 0; ii < 2; ++ii) a[ii] += __shfl_xor(a[ii], o);
      if (j == 0){
        float bb = cbv[gcol];
#pragma unroll
        for (int ii = 0; ii < 2; ++ii) qout[(long)(b*S_ + i0 + ii)*D_ + gcol] = a[ii] + bb;
      }
    }
  }
}

// ---------------- host ------------------------------------------------------
extern "C" void kernel_launch(void* const* d_in, const int* in_sizes, int n_in,
                              void* d_out, int out_size, void* d_ws, size_t ws_size,
                              hipStream_t stream)
{
  const float* inputs     = (const float*)d_in[0];
  const float* slots_init = (const float*)d_in[1];
  const float* slots_mu   = (const float*)d_in[2];
  const float* slots_sig  = (const float*)d_in[3];
  const float* wq   = (const float*)d_in[4];
  const float* bq   = (const float*)d_in[5];
  const float* wk   = (const float*)d_in[6];
  const float* bk   = (const float*)d_in[7];
  const float* wv   = (const float*)d_in[8];
  const float* bv   = (const float*)d_in[9];
  const float* w_ih = (const float*)d_in[10];
  const float* b_ih = (const float*)d_in[11];
  const float* w_hh = (const float*)d_in[12];
  const float* b_hh = (const float*)d_in[13];
  const float* w1   = (const float*)d_in[14];
  const float* b1   = (const float*)d_in[15];
  const float* w2   = (const float*)d_in[16];
  const float* b2   = (const float*)d_in[17];
  const float* lig  = (const float*)d_in[18];
  const float* lib  = (const float*)d_in[19];
  const float* lsg  = (const float*)d_in[20];
  const float* lsb  = (const float*)d_in[21];
  const float* ffg  = (const float*)d_in[22];
  const float* ffb  = (const float*)d_in[23];
  float* out = (float*)d_out;

  // ws layout (~145.7 MB) — R14 proven. No memsets.
  //   qt    @ 0          (524,288)
  //   numP  @ 524,288    (8,388,608)   16-chunk partials
  //   denP  @ 8,912,896  (32,768)      [b][i][ch]
  //   dbuf  @ 8,945,664  (2,048)
  //   Mb    @ 8,947,712  (262,144)     f32 (kI)
  //   cb    @ 9,209,856  (1,024)
  //   v1b   @ 9,210,880  (1,024)
  //   c0b   @ 9,211,904  (1,024)
  //   bih2  @ 9,212,928  (4,096)
  //   Mbh   @ 9,217,024  (131,072)     bf16 (kS)
  //   Wih2h @ 9,348,096  (393,216)     bf16
  //   whhh  @ 9,741,312  (393,216)     bf16
  //   w1h   @ 10,134,528 (262,144)     bf16
  //   w2h   @ 10,396,672 (262,144)     bf16
  //   xh    @ 10,658,816 (134,217,728) x_hat bf16 (L3-resident)
  // slots lives in d_out (in-place across iterations).
  char* ws = (char*)d_ws;
  float* qtb  = (float*)(ws);
  float* numP = (float*)(ws + 524288);
  float* denP = (float*)(ws + 8912896);
  float* dbuf = (float*)(ws + 8945664);
  float* Mb   = (float*)(ws + 8947712);
  float* cb   = (float*)(ws + 9209856);
  float* v1b  = (float*)(ws + 9210880);
  float* c0b  = (float*)(ws + 9211904);
  float* bih2 = (float*)(ws + 9212928);
  unsigned short* Mbh   = (unsigned short*)(ws + 9217024);
  unsigned short* Wih2h = (unsigned short*)(ws + 9348096);
  unsigned short* whhh  = (unsigned short*)(ws + 9741312);
  unsigned short* w1h   = (unsigned short*)(ws + 10134528);
  unsigned short* w2h   = (unsigned short*)(ws + 10396672);
  unsigned short* xh    = (unsigned short*)(ws + 10658816);
  float* slots = out;

  kLN<<<2048, 256, 0, stream>>>(inputs, lig, lib, xh);
  kPre<<<1857, 256, 0, stream>>>(wq, bq, wk, bk, wv, bv, w_ih, b_ih,
                                 w_hh, w1, w2,
                                 Mb, cb, v1b, c0b, bih2, Mbh, Wih2h,
                                 whhh, w1h, w2h);
  kI<<<64, 256, 0, stream>>>(slots_init, slots_mu, slots_sig, lsg, lsb,
                             Mb, cb, v1b, c0b, slots, qtb, dbuf);
  for (int it = 0; it < 3; ++it){
    kD<<<dim3(NCH_, B_), 256, 0, stream>>>(xh, qtb, dbuf, numP, denP);
    kS<<<256, 256, 0, stream>>>(numP, denP, slots, Wih2h, bih2, whhh, b_hh,
                                w1h, b1, w2h, b2, ffg, ffb, lsg, lsb,
                                Mbh, cb, v1b, c0b,
                                slots, qtb, dbuf, (it < 2) ? 1 : 0);
  }
}

// Round 17
// 410.996 us; speedup vs baseline: 1.1803x; 1.1155x over previous
//
#include <hip/hip_runtime.h>
#include <hip/hip_bf16.h>

#define B_ 64
#define N_ 4096
#define D_ 256
#define S_ 8
#define HID_ 512
#define NCH_ 16

typedef __attribute__((ext_vector_type(8))) short short8;
typedef __attribute__((ext_vector_type(4))) float f32x4;

__device__ inline unsigned int f2bf(float f){
  unsigned int x = __builtin_bit_cast(unsigned int, f);
  unsigned int r = x + 0x7fffu + ((x >> 16) & 1u);
  return (r >> 16);
}
__device__ inline float bf2f(unsigned int u){
  unsigned int x = (u & 0xffffu) << 16;
  return __builtin_bit_cast(float, x);
}
__device__ inline void fma8(short8 w8, const float* xp, float& a){
#pragma unroll
  for (int e = 0; e < 8; ++e) a += bf2f((unsigned)(unsigned short)w8[e]) * xp[e];
}

// ---------------- kernel LN: x_hat = LN(inputs) -> bf16 [B*N][256] ----------
__global__ __launch_bounds__(256) void kLN(const float* __restrict__ xin,
    const float* __restrict__ lng, const float* __restrict__ lnb,
    unsigned short* __restrict__ xh)
{
  const int t = threadIdx.x;
  const int wv = t >> 6, lane = t & 63;
  const float4 g4 = *(const float4*)(lng + lane * 4);
  const float4 b4 = *(const float4*)(lnb + lane * 4);
#pragma unroll 2
  for (int it = 0; it < 32; ++it){
    const long r = (long)it * 8192 + blockIdx.x * 4 + wv;
    float4 f = *(const float4*)(xin + r * 256 + lane * 4);
    float s  = f.x + f.y + f.z + f.w;
    float ss = f.x*f.x + f.y*f.y + f.z*f.z + f.w*f.w;
#pragma unroll
    for (int o = 1; o < 64; o <<= 1){ s += __shfl_xor(s, o); ss += __shfl_xor(ss, o); }
    const float mean = s * (1.f/256.f);
    const float rstd = rsqrtf(ss * (1.f/256.f) - mean * mean + 1e-5f);
    unsigned p0 = f2bf((f.x - mean)*rstd*g4.x + b4.x) | (f2bf((f.y - mean)*rstd*g4.y + b4.y) << 16);
    unsigned p1 = f2bf((f.z - mean)*rstd*g4.z + b4.z) | (f2bf((f.w - mean)*rstd*g4.w + b4.w) << 16);
    uint2 pk; pk.x = p0; pk.y = p1;
    *(uint2*)(xh + r * 256 + lane * 4) = pk;
  }
}

// ---------------- kernel Pre: fold weights (also emits bf16 copies) ---------
__global__ __launch_bounds__(256) void kPre(
    const float* __restrict__ wq, const float* __restrict__ bq,
    const float* __restrict__ wk, const float* __restrict__ bk,
    const float* __restrict__ wv, const float* __restrict__ bv,
    const float* __restrict__ wih, const float* __restrict__ bih,
    float* __restrict__ Mb, float* __restrict__ cb,
    float* __restrict__ v1b, float* __restrict__ c0b,
    float* __restrict__ bih2,
    unsigned short* __restrict__ Mbh, unsigned short* __restrict__ Wih2h)
{
  const int blk = blockIdx.x, t = threadIdx.x;
  if (blk < 256){
    const int d = blk;
    float acc = 0.f, accc = 0.f;
    for (int e = 0; e < 256; ++e){
      float wkd = wk[e*256 + d];
      acc  += wkd * wq[e*256 + t];
      accc += wkd * bq[e];
    }
    Mb[d*256 + t] = acc;
    Mbh[d*256 + t] = (unsigned short)f2bf(acc);
    if (t == 0) cb[d] = accc;
  } else if (blk < 1024){
    const int g = blk - 256;
    float acc = 0.f, accb = 0.f;
    for (int d = 0; d < 256; ++d){
      float wg = wih[g*256 + d];
      acc  += wg * wv[d*256 + t];
      accb += wg * bv[d];
    }
    Wih2h[g*256 + t] = (unsigned short)f2bf(acc);
    if (t == 0) bih2[g] = bih[g] + accb;
  } else {
    float acc = 0.f, acc0 = 0.f;
    for (int e = 0; e < 256; ++e){
      float bke = bk[e];
      acc  += wq[e*256 + t] * bke;
      acc0 += bq[e] * bke;
    }
    v1b[t] = acc;
    if (t == 0) c0b[0] = acc0;
  }
}

// ---------------- kernel Cvt: w_hh / w1 / w2 -> bf16 ------------------------
__global__ __launch_bounds__(256) void kCvt(
    const float* __restrict__ w_hh, const float* __restrict__ w1,
    const float* __restrict__ w2,
    unsigned short* __restrict__ whhh, unsigned short* __restrict__ w1h,
    unsigned short* __restrict__ w2h)
{
  const int i = blockIdx.x * 256 + threadIdx.x;     // 0 .. 458751
  if (i < 196608) whhh[i] = (unsigned short)f2bf(w_hh[i]);
  else if (i < 327680) w1h[i - 196608] = (unsigned short)f2bf(w1[i - 196608]);
  else w2h[i - 327680] = (unsigned short)f2bf(w2[i - 327680]);
}

// ---------------- kernel I: slots init; qt = LN(slots)@M^T + c; d = s.v1+c0 --
__global__ __launch_bounds__(256) void kI(const float* __restrict__ init,
    const float* __restrict__ mu, const float* __restrict__ sig,
    const float* __restrict__ lsg, const float* __restrict__ lsb,
    const float* __restrict__ Mb, const float* __restrict__ cb,
    const float* __restrict__ v1b, const float* __restrict__ c0b,
    float* __restrict__ slots, float* __restrict__ qt, float* __restrict__ dbuf)
{
  const int b = blockIdx.x, t = threadIdx.x;
  __shared__ float xs[S_ * D_];
  __shared__ float red[4 * S_ * 2];
  __shared__ float redd[4 * S_];
  float sv[S_];
  const float muv = mu[t], sgv = sig[t];
#pragma unroll
  for (int i = 0; i < S_; ++i){
    float x = muv + sgv * init[(b*S_ + i)*D_ + t];
    sv[i] = x;
    slots[(b*S_ + i)*D_ + t] = x;
  }
  float s[S_], qq[S_];
#pragma unroll
  for (int i = 0; i < S_; ++i){ s[i] = sv[i]; qq[i] = sv[i]*sv[i]; }
#pragma unroll
  for (int o = 1; o < 64; o <<= 1){
#pragma unroll
    for (int i = 0; i < S_; ++i){ s[i] += __shfl_xor(s[i], o); qq[i] += __shfl_xor(qq[i], o); }
  }
  const int wv_ = t >> 6;
  if ((t & 63) == 0){
#pragma unroll
    for (int i = 0; i < S_; ++i){ red[(wv_*S_ + i)*2] = s[i]; red[(wv_*S_ + i)*2 + 1] = qq[i]; }
  }
  __syncthreads();
  const float g_ = lsg[t], bv_ = lsb[t];
#pragma unroll
  for (int i = 0; i < S_; ++i){
    float S0 = 0.f, Q0 = 0.f;
#pragma unroll
    for (int w2 = 0; w2 < 4; ++w2){ S0 += red[(w2*S_ + i)*2]; Q0 += red[(w2*S_ + i)*2 + 1]; }
    float mean = S0 * (1.f/256.f), var = Q0 * (1.f/256.f) - mean*mean;
    float rstd = rsqrtf(var + 1e-5f);
    xs[i*D_ + t] = (sv[i] - mean) * rstd * g_ + bv_;
  }
  __syncthreads();
  // ---- d_i = s_hat . v1 + c0
  {
    const float v1v = v1b[t];
    float pd[S_];
#pragma unroll
    for (int i = 0; i < S_; ++i) pd[i] = xs[i*D_ + t] * v1v;
#pragma unroll
    for (int o = 1; o < 64; o <<= 1)
#pragma unroll
      for (int i = 0; i < S_; ++i) pd[i] += __shfl_xor(pd[i], o);
    if ((t & 63) == 0){
#pragma unroll
      for (int i = 0; i < S_; ++i) redd[wv_*S_ + i] = pd[i];
    }
    __syncthreads();
    if (t < S_) dbuf[b*S_ + t] = redd[t] + redd[S_ + t] + redd[2*S_ + t] + redd[3*S_ + t] + c0b[0];
  }
  // ---- qt = s_hat @ M^T + c
  const float4* wr = (const float4*)(Mb + (long)t * D_);
  float acc[S_];
#pragma unroll
  for (int i = 0; i < S_; ++i) acc[i] = 0.f;
  for (int kc = 0; kc < 64; ++kc){
    float4 wf = wr[kc];
#pragma unroll
    for (int i = 0; i < S_; ++i){
      float4 xf = *(const float4*)(xs + i*D_ + kc*4);
      acc[i] += wf.x*xf.x + wf.y*xf.y + wf.z*xf.z + wf.w*xf.w;
    }
  }
  const float cbv = cb[t];
#pragma unroll
  for (int i = 0; i < S_; ++i) qt[(b*S_ + i)*D_ + t] = acc[i] + cbv;
}

// ---------------- kernel D: dots -> softmax -> PV (R12 proven version) ------
__global__ __launch_bounds__(256) void kD(const unsigned short* __restrict__ xh,
    const float* __restrict__ qt, const float* __restrict__ dbuf,
    float* __restrict__ numP, float* __restrict__ denP)
{
  const int b = blockIdx.y, ch = blockIdx.x, t = threadIdx.x;
  __shared__ __align__(16) char smem[4 * 64 * 37 * 4];      // qs overlay / redbuf
  __shared__ __align__(16) float sw[128 * 8];               // [row][slot]
  unsigned short* qs = (unsigned short*)smem;               // 16 x 264
  float* redbuf = (float*)smem;                             // 4 x 64 x 37
  const int lane = t & 63, w = t >> 6;
  const int lr = lane & 15, lg = lane >> 4;
  const int oct = lane & 31, sh = lane >> 5;

  { // build qs (rows 0..7 = qt bf16, rows 8..15 = 0)
    const int rowq = t >> 4, segq = t & 15;
    uint4 z0 = {0,0,0,0}, z1 = {0,0,0,0};
    if (rowq < 8){
      const float* qr = qt + ((long)b * S_ + rowq) * D_ + segq * 16;
      float4 f0 = ((const float4*)qr)[0], f1 = ((const float4*)qr)[1];
      float4 f2 = ((const float4*)qr)[2], f3 = ((const float4*)qr)[3];
      z0.x = f2bf(f0.x)|(f2bf(f0.y)<<16); z0.y = f2bf(f0.z)|(f2bf(f0.w)<<16);
      z0.z = f2bf(f1.x)|(f2bf(f1.y)<<16); z0.w = f2bf(f1.z)|(f2bf(f1.w)<<16);
      z1.x = f2bf(f2.x)|(f2bf(f2.y)<<16); z1.y = f2bf(f2.z)|(f2bf(f2.w)<<16);
      z1.z = f2bf(f3.x)|(f2bf(f3.y)<<16); z1.w = f2bf(f3.z)|(f2bf(f3.w)<<16);
    }
    *(uint4*)(qs + rowq*264 + segq*16) = z0;
    *(uint4*)(qs + rowq*264 + segq*16 + 8) = z1;
  }
  __syncthreads();

  short8 bqf[8];
#pragma unroll
  for (int ks = 0; ks < 8; ++ks)
    bqf[ks] = *(const short8*)(qs + lr*264 + ks*32 + lg*8);
  __syncthreads();                         // qs dead; redbuf may reuse smem

  const float dd = (lr < 8) ? dbuf[b*S_ + lr] * 0.0625f : 0.f;

  float acc4[4][8];
#pragma unroll
  for (int s = 0; s < 4; ++s)
#pragma unroll
    for (int e = 0; e < 8; ++e) acc4[s][e] = 0.f;
  float den4[4] = {0.f, 0.f, 0.f, 0.f};

  for (int ph = 0; ph < 2; ++ph){
    const long j0 = (long)ch * 256 + ph * 128;
    // ---- dots: wave w owns rows w*32 .. +32 (writes wave-private sw rows)
#pragma unroll
    for (int tau = 0; tau < 2; ++tau){
      const long jt = j0 + w*32 + tau*16;
      const unsigned short* kr = xh + ((long)b * N_ + jt + lr) * 256;
      f32x4 d = {0,0,0,0};
#pragma unroll
      for (int ks = 0; ks < 8; ++ks){
        short8 afk = *(const short8*)(kr + ks*32 + lg*8);
        d = __builtin_amdgcn_mfma_f32_16x16x32_bf16(afk, bqf[ks], d, 0, 0, 0);
      }
#pragma unroll
      for (int r = 0; r < 4; ++r){
        float x = d[r] * 0.0625f + dd;                // SCALE*(qt.xh) + d_i
        float m = x;
        m = fmaxf(m, __shfl_xor(m, 1));
        m = fmaxf(m, __shfl_xor(m, 2));
        m = fmaxf(m, __shfl_xor(m, 4));
        float e = __expf(x - m);
        float ssum = e;
        ssum += __shfl_xor(ssum, 1);
        ssum += __shfl_xor(ssum, 2);
        ssum += __shfl_xor(ssum, 4);
        float wv = e / ssum + 1e-8f;
        if (lr < 8) sw[(w*32 + tau*16 + lg*4 + r)*8 + lr] = wv;
      }
    }
    // (no barrier: sw rows w*32..+32 written & read by wave w only)
    // ---- PV: wave reads its 32 rows once; lane covers 4 slots x 8 d-elems
    const unsigned short* vrow = xh + ((long)b * N_ + j0 + w*32) * 256 + oct*8;
    const float* swr = sw + (w*32)*8 + sh*4;
#pragma unroll 4
    for (int j = 0; j < 32; ++j){
      uint4 v = *(const uint4*)(vrow + (long)j * 256);
      float4 w4 = *(const float4*)(swr + j*8);
      float xv[8];
      xv[0] = bf2f(v.x); xv[1] = bf2f(v.x >> 16);
      xv[2] = bf2f(v.y); xv[3] = bf2f(v.y >> 16);
      xv[4] = bf2f(v.z); xv[5] = bf2f(v.z >> 16);
      xv[6] = bf2f(v.w); xv[7] = bf2f(v.w >> 16);
#pragma unroll
      for (int e = 0; e < 8; ++e){
        acc4[0][e] += w4.x * xv[e];
        acc4[1][e] += w4.y * xv[e];
        acc4[2][e] += w4.z * xv[e];
        acc4[3][e] += w4.w * xv[e];
      }
      den4[0] += w4.x; den4[1] += w4.y; den4[2] += w4.z; den4[3] += w4.w;
    }
  }

  // ---- cross-wave reduce via redbuf (stride 37: conflict-free)
  __syncthreads();                         // all waves done with dots/PV
  {
    float* myred = redbuf + (w*64 + lane)*37;
#pragma unroll
    for (int s = 0; s < 4; ++s){
#pragma unroll
      for (int e = 0; e < 8; ++e) myred[s*8 + e] = acc4[s][e];
      myred[32 + s] = den4[s];
    }
  }
  __syncthreads();
  {
    const int i_ = t >> 5, oo = t & 31;
    const int ssh = i_ >> 2, ss = i_ & 3;
    float outv[8] = {0,0,0,0,0,0,0,0};
    float den = 0.f;
#pragma unroll
    for (int wv2 = 0; wv2 < 4; ++wv2){
      const float* p = redbuf + (wv2*64 + ssh*32 + oo)*37;
#pragma unroll
      for (int e = 0; e < 8; ++e) outv[e] += p[ss*8 + e];
      den += p[32 + ss];
    }
    float* numC = numP + ((((long)ch * B_ + b) * S_ + i_) * D_) + oo * 8;
    float4 a0 = {outv[0], outv[1], outv[2], outv[3]};
    float4 a1 = {outv[4], outv[5], outv[6], outv[7]};
    *(float4*)(numC) = a0;
    *(float4*)(numC + 4) = a1;
    if (oo == 0) denP[((long)b * S_ + i_) * NCH_ + ch] = den;
  }
}

// ---------------- kernel S: bf16 weights, u -> GRU -> MLP -> (qt|out) -------
__device__ inline void stats2(const float v[2], float* red, int t, float* mean, float* rstd){
  float s[2], q2[2];
#pragma unroll
  for (int ii = 0; ii < 2; ++ii){ s[ii] = v[ii]; q2[ii] = v[ii]*v[ii]; }
#pragma unroll
  for (int o = 1; o < 64; o <<= 1){
#pragma unroll
    for (int ii = 0; ii < 2; ++ii){ s[ii] += __shfl_xor(s[ii], o); q2[ii] += __shfl_xor(q2[ii], o); }
  }
  const int wv = t >> 6;
  if ((t & 63) == 0){
#pragma unroll
    for (int ii = 0; ii < 2; ++ii){ red[(wv*2 + ii)*2] = s[ii]; red[(wv*2 + ii)*2 + 1] = q2[ii]; }
  }
  __syncthreads();
#pragma unroll
  for (int ii = 0; ii < 2; ++ii){
    float S0 = 0.f, Q0 = 0.f;
#pragma unroll
    for (int w2 = 0; w2 < 4; ++w2){ S0 += red[(w2*2 + ii)*2]; Q0 += red[(w2*2 + ii)*2 + 1]; }
    float m = S0 * (1.f/256.f);
    float var = Q0 * (1.f/256.f) - m*m;
    mean[ii] = m; rstd[ii] = rsqrtf(var + 1e-5f);
  }
  __syncthreads();
}

__global__ __launch_bounds__(256) void kS(
    const float* __restrict__ numP, const float* __restrict__ denP,
    const float* __restrict__ slots_in,
    const unsigned short* __restrict__ Wih2h, const float* __restrict__ bih2,
    const unsigned short* __restrict__ whhh, const float* __restrict__ b_hh,
    const unsigned short* __restrict__ w1h, const float* __restrict__ b1,
    const unsigned short* __restrict__ w2h, const float* __restrict__ b2,
    const float* __restrict__ fg, const float* __restrict__ fb,
    const float* __restrict__ lsg, const float* __restrict__ lsb,
    const unsigned short* __restrict__ Mbh, const float* __restrict__ cbv,
    const float* __restrict__ v1b, const float* __restrict__ c0b,
    float* __restrict__ outp, float* __restrict__ qout, float* __restrict__ dbuf,
    int write_q)
{
  const int blk = blockIdx.x;            // 0..255
  const int b = blk >> 2, i0 = (blk & 3) * 2;
  const int t = threadIdx.x;
  const int grp = t >> 3, j = t & 7;
  __shared__ float us[2][D_], hs[2][D_], xs2[2][D_];
  __shared__ float gi_l[2][768], gh_l[2][768];
  __shared__ float h2s[2][HID_];
  __shared__ float o2[2][D_];
  __shared__ float red[4 * 2 * 2];
  const long base = (long)(b * S_ + i0) * D_;
#pragma unroll
  for (int ii = 0; ii < 2; ++ii){
    int si = b*S_ + i0 + ii;
    float dv = 0.f;
#pragma unroll
    for (int ch = 0; ch < NCH_; ++ch) dv += denP[(long)si * NCH_ + ch];
    float u = 0.f;
    for (int ch = 0; ch < NCH_; ++ch)
      u += numP[(((long)ch * B_ + b) * S_ + i0 + ii) * D_ + t];
    us[ii][t] = u / dv;
    hs[ii][t] = slots_in[base + ii*D_ + t];
  }
  __syncthreads();
  // ---- GRU gate GEMMs (bf16 weights): gi = u @ Wih2^T + bih2 ; gh = h @ w_hh^T
  for (int q = 0; q < 24; ++q){
    const int gcol = grp + q * 32;
    const short8* wi = (const short8*)(Wih2h + (long)gcol * D_);
    const short8* wh = (const short8*)(whhh + (long)gcol * D_);
    float ai[2] = {0,0}, ah[2] = {0,0};
#pragma unroll
    for (int c = 0; c < 4; ++c){
      const int u = j + c*8;               // short8 unit (covers cols u*8..+7)
      short8 wf = wi[u];
      short8 hf = wh[u];
#pragma unroll
      for (int ii = 0; ii < 2; ++ii){
        fma8(wf, &us[ii][u*8], ai[ii]);
        fma8(hf, &hs[ii][u*8], ah[ii]);
      }
    }
#pragma unroll
    for (int o = 1; o < 8; o <<= 1){
#pragma unroll
      for (int ii = 0; ii < 2; ++ii){ ai[ii] += __shfl_xor(ai[ii], o); ah[ii] += __shfl_xor(ah[ii], o); }
    }
    if (j == 0){
#pragma unroll
      for (int ii = 0; ii < 2; ++ii){ gi_l[ii][gcol] = ai[ii]; gh_l[ii][gcol] = ah[ii]; }
    }
  }
  __syncthreads();
  const float bir = bih2[t], biz = bih2[256 + t], bin_ = bih2[512 + t];
  const float bhr = b_hh[t], bhz = b_hh[256 + t], bhn = b_hh[512 + t];
  float nh[2];
#pragma unroll
  for (int ii = 0; ii < 2; ++ii){
    float r = 1.f / (1.f + __expf(-(gi_l[ii][t] + bir + gh_l[ii][t] + bhr)));
    float z = 1.f / (1.f + __expf(-(gi_l[ii][256 + t] + biz + gh_l[ii][256 + t] + bhz)));
    float n = tanhf(gi_l[ii][512 + t] + bin_ + r * (gh_l[ii][512 + t] + bhn));
    nh[ii] = (1.f - z) * n + z * hs[ii][t];
  }
  float mean[2], rstd[2];
  stats2(nh, red, t, mean, rstd);
  const float fgv = fg[t], fbv = fb[t];
#pragma unroll
  for (int ii = 0; ii < 2; ++ii) xs2[ii][t] = (nh[ii] - mean[ii]) * rstd[ii] * fgv + fbv;
  __syncthreads();
  // ---- MLP1 (bf16 weights) + relu
  for (int q = 0; q < 16; ++q){
    const int gcol = grp + q * 32;
    const short8* wr = (const short8*)(w1h + (long)gcol * D_);
    float a[2] = {0,0};
#pragma unroll
    for (int c = 0; c < 4; ++c){
      const int u = j + c*8;
      short8 wf = wr[u];
#pragma unroll
      for (int ii = 0; ii < 2; ++ii) fma8(wf, &xs2[ii][u*8], a[ii]);
    }
#pragma unroll
    for (int o = 1; o < 8; o <<= 1)
#pragma unroll
      for (int ii = 0; ii < 2; ++ii) a[ii] += __shfl_xor(a[ii], o);
    if (j == 0){
      float bb = b1[gcol];
#pragma unroll
      for (int ii = 0; ii < 2; ++ii) h2s[ii][gcol] = fmaxf(a[ii] + bb, 0.f);
    }
  }
  __syncthreads();
  // ---- MLP2 (bf16 weights, K=512)
  for (int q = 0; q < 8; ++q){
    const int gcol = grp + q * 32;
    const short8* wr = (const short8*)(w2h + (long)gcol * HID_);
    float a[2] = {0,0};
#pragma unroll
    for (int c = 0; c < 8; ++c){
      const int u = j + c*8;
      short8 wf = wr[u];
#pragma unroll
      for (int ii = 0; ii < 2; ++ii) fma8(wf, &h2s[ii][u*8], a[ii]);
    }
#pragma unroll
    for (int o = 1; o < 8; o <<= 1)
#pragma unroll
      for (int ii = 0; ii < 2; ++ii) a[ii] += __shfl_xor(a[ii], o);
    if (j == 0){
#pragma unroll
      for (int ii = 0; ii < 2; ++ii) o2[ii][gcol] = a[ii];
    }
  }
  __syncthreads();
  float outv[2];
  const float b2v = b2[t];
#pragma unroll
  for (int ii = 0; ii < 2; ++ii){
    outv[ii] = nh[ii] + o2[ii][t] + b2v;
    outp[base + ii*D_ + t] = outv[ii];
  }
  if (write_q){
    float mean2[2], rstd2[2];
    stats2(outv, red, t, mean2, rstd2);
    const float lg2 = lsg[t], lb2 = lsb[t];
#pragma unroll
    for (int ii = 0; ii < 2; ++ii) xs2[ii][t] = (outv[ii] - mean2[ii]) * rstd2[ii] * lg2 + lb2;
    __syncthreads();
    // ---- d_i = s_hat . v1 + c0
    {
      const float v1v = v1b[t];
      float pd[2];
#pragma unroll
      for (int ii = 0; ii < 2; ++ii) pd[ii] = xs2[ii][t] * v1v;
#pragma unroll
      for (int o = 1; o < 64; o <<= 1)
#pragma unroll
        for (int ii = 0; ii < 2; ++ii) pd[ii] += __shfl_xor(pd[ii], o);
      const int wv = t >> 6;
      if ((t & 63) == 0){ red[wv*2] = pd[0]; red[wv*2 + 1] = pd[1]; }
      __syncthreads();
      if (t < 2) dbuf[b*S_ + i0 + t] = red[t] + red[2 + t] + red[4 + t] + red[6 + t] + c0b[0];
    }
    // ---- qt = s_hat @ M^T + c (bf16 M)
    for (int q = 0; q < 8; ++q){
      const int gcol = grp + q * 32;
      const short8* wr = (const short8*)(Mbh + (long)gcol * D_);
      float a[2] = {0,0};
#pragma unroll
      for (int c = 0; c < 4; ++c){
        const int u = j + c*8;
        short8 wf = wr[u];
#pragma unroll
        for (int ii = 0; ii < 2; ++ii) fma8(wf, &xs2[ii][u*8], a[ii]);
      }
#pragma unroll
      for (int o = 1; o < 8; o <<= 1)
#pragma unroll
        for (int ii = 0; ii < 2; ++ii) a[ii] += __shfl_xor(a[ii], o);
      if (j == 0){
        float bb = cbv[gcol];
#pragma unroll
        for (int ii = 0; ii < 2; ++ii) qout[(long)(b*S_ + i0 + ii)*D_ + gcol] = a[ii] + bb;
      }
    }
  }
}

// ---------------- host ------------------------------------------------------
extern "C" void kernel_launch(void* const* d_in, const int* in_sizes, int n_in,
                              void* d_out, int out_size, void* d_ws, size_t ws_size,
                              hipStream_t stream)
{
  const float* inputs     = (const float*)d_in[0];
  const float* slots_init = (const float*)d_in[1];
  const float* slots_mu   = (const float*)d_in[2];
  const float* slots_sig  = (const float*)d_in[3];
  const float* wq   = (const float*)d_in[4];
  const float* bq   = (const float*)d_in[5];
  const float* wk   = (const float*)d_in[6];
  const float* bk   = (const float*)d_in[7];
  const float* wv   = (const float*)d_in[8];
  const float* bv   = (const float*)d_in[9];
  const float* w_ih = (const float*)d_in[10];
  const float* b_ih = (const float*)d_in[11];
  const float* w_hh = (const float*)d_in[12];
  const float* b_hh = (const float*)d_in[13];
  const float* w1   = (const float*)d_in[14];
  const float* b1   = (const float*)d_in[15];
  const float* w2   = (const float*)d_in[16];
  const float* b2   = (const float*)d_in[17];
  const float* lig  = (const float*)d_in[18];
  const float* lib  = (const float*)d_in[19];
  const float* lsg  = (const float*)d_in[20];
  const float* lsb  = (const float*)d_in[21];
  const float* ffg  = (const float*)d_in[22];
  const float* ffb  = (const float*)d_in[23];
  float* out = (float*)d_out;

  // ws layout (~145.7 MB). No memsets: numP/denP fully overwritten every kD.
  //   qt    @ 0          (524,288)
  //   numP  @ 524,288    (8,388,608)   16-chunk partials
  //   denP  @ 8,912,896  (32,768)      [b][i][ch]
  //   dbuf  @ 8,945,664  (2,048)
  //   Mb    @ 8,947,712  (262,144)     f32 (kI)
  //   cb    @ 9,209,856  (1,024)
  //   v1b   @ 9,210,880  (1,024)
  //   c0b   @ 9,211,904  (1,024)
  //   bih2  @ 9,212,928  (4,096)
  //   Mbh   @ 9,217,024  (131,072)     bf16 (kS)
  //   Wih2h @ 9,348,096  (393,216)     bf16
  //   whhh  @ 9,741,312  (393,216)     bf16
  //   w1h   @ 10,134,528 (262,144)     bf16
  //   w2h   @ 10,396,672 (262,144)     bf16
  //   xh    @ 10,658,816 (134,217,728) x_hat bf16 (L3-resident)
  // slots lives in d_out (in-place across iterations).
  char* ws = (char*)d_ws;
  float* qtb  = (float*)(ws);
  float* numP = (float*)(ws + 524288);
  float* denP = (float*)(ws + 8912896);
  float* dbuf = (float*)(ws + 8945664);
  float* Mb   = (float*)(ws + 8947712);
  float* cb   = (float*)(ws + 9209856);
  float* v1b  = (float*)(ws + 9210880);
  float* c0b  = (float*)(ws + 9211904);
  float* bih2 = (float*)(ws + 9212928);
  unsigned short* Mbh   = (unsigned short*)(ws + 9217024);
  unsigned short* Wih2h = (unsigned short*)(ws + 9348096);
  unsigned short* whhh  = (unsigned short*)(ws + 9741312);
  unsigned short* w1h   = (unsigned short*)(ws + 10134528);
  unsigned short* w2h   = (unsigned short*)(ws + 10396672);
  unsigned short* xh    = (unsigned short*)(ws + 10658816);
  float* slots = out;

  kLN<<<2048, 256, 0, stream>>>(inputs, lig, lib, xh);
  kPre<<<1025, 256, 0, stream>>>(wq, bq, wk, bk, wv, bv, w_ih, b_ih,
                                 Mb, cb, v1b, c0b, bih2, Mbh, Wih2h);
  kCvt<<<1792, 256, 0, stream>>>(w_hh, w1, w2, whhh, w1h, w2h);
  kI<<<64, 256, 0, stream>>>(slots_init, slots_mu, slots_sig, lsg, lsb,
                             Mb, cb, v1b, c0b, slots, qtb, dbuf);
  for (int it = 0; it < 3; ++it){
    kD<<<dim3(NCH_, B_), 256, 0, stream>>>(xh, qtb, dbuf, numP, denP);
    kS<<<256, 256, 0, stream>>>(numP, denP, slots, Wih2h, bih2, whhh, b_hh,
                                w1h, b1, w2h, b2, ffg, ffb, lsg, lsb,
                                Mbh, cb, v1b, c0b,
                                slots, qtb, dbuf, (it < 2) ? 1 : 0);
  }
}